// Round 6
// baseline (131.700 us; speedup 1.0000x reference)
//
#include <hip/hip_runtime.h>
#include <math.h>

#define B_ 8
#define C_ 64
#define M_ 512            // B_*C_
#define T_ 1200
#define TP2 1280          // T padded to 128
#define KP 4864           // K padded (K = 4800)
#define K2P 9728          // 2*KP interleaved cos/sin
#define SPLITK 8
#define KCH 1216          // K2P/SPLITK halves
#define NS1 20            // TP2/64 reduction steps (gemm1)
#define NS2 19            // KCH/64 reduction steps (gemm2)

#ifndef M_PI
#define M_PI 3.14159265358979323846
#endif

typedef _Float16 h8 __attribute__((ext_vector_type(8)));
typedef float f32x16 __attribute__((ext_vector_type(16)));
union H8 { h8 h; float4 v; _Float16 e[8]; };
union H4 { _Float16 e[4]; float2 v; };
union HP { _Float16 hh[2]; unsigned u; };
union F4U { float4 v; float f[4]; };

#define Z16v {0.f,0.f,0.f,0.f,0.f,0.f,0.f,0.f,0.f,0.f,0.f,0.f,0.f,0.f,0.f,0.f}
#define MFMA32(a, b, c) __builtin_amdgcn_mfma_f32_32x32x16_f16(a, b, c, 0, 0, 0)

__device__ __forceinline__ float2 cmul(float2 a, float2 b) {
    return make_float2(a.x * b.x - a.y * b.y, a.y * b.x + a.x * b.y);
}

// async global->LDS, 16B per lane (dest resolves to wave base + lane*16)
__device__ __forceinline__ void gload16(const void* g, void* l) {
    __builtin_amdgcn_global_load_lds(
        (const __attribute__((address_space(1))) unsigned int*)g,
        (__attribute__((address_space(3))) unsigned int*)l, 16, 0, 0);
}

// ---------------- mask mode detect (256-thread blocks) + value fetch ----------------
__device__ int detect_mode(const void* mask_raw) {
    __shared__ int sb0, sb1;
    if (threadIdx.x == 0) { sb0 = 0; sb1 = 0; }
    __syncthreads();
    const unsigned* wi = (const unsigned*)mask_raw;
    const float* wf = (const float*)mask_raw;
    int nw = (B_ * T_) >> 2;
    int badI = 0, badF = 0;
    for (int i = threadIdx.x; i < nw; i += blockDim.x) {
        unsigned v = wi[i];
        badI |= (v > 1u);
        float f = wf[i];
        badF |= !(f == 0.0f || f == 1.0f);
    }
    if (badI) sb0 = 1;
    if (badF) sb1 = 1;
    __syncthreads();
    return (!sb0) ? 0 : ((!sb1) ? 1 : 2);
}

__device__ __forceinline__ float mval(const void* mask_raw, int mode, int idx) {
    if (mode == 0) return (float)((const int*)mask_raw)[idx];
    if (mode == 1) return ((const float*)mask_raw)[idx];
    return (float)((const unsigned char*)mask_raw)[idx];
}

// ---------------- basis (blocks 0..303) + prep_dm (blocks 304..313) ----------------
// 16-k stripes over full T: generates Z[k2][t], ZT[t][k2] (f16), tau sums -> phi
// fully in-block (rot tables from 2 dp sincos per k; cnt accumulated exactly).
__global__ __launch_bounds__(256) void basisC_kernel(
    const void* __restrict__ mask, const float* __restrict__ data,
    _Float16* __restrict__ Zb, _Float16* __restrict__ ZT, _Float16* __restrict__ dm,
    float* __restrict__ cphi, float* __restrict__ sphi,
    float* __restrict__ rdcv, float* __restrict__ rdsv,
    int K, double fstep) {
    int tid = threadIdx.x;
    int mode = detect_mode(mask);
    if (blockIdx.x >= 304) {
        // prep_dm: dm[bc][TP2] = f16(data * m)
        int bid2 = blockIdx.x - 304;   // 0..9
        for (int it = 0; it < 32; it++) {
            int idx8 = it * 2560 + bid2 * 256 + tid;   // 81920 chunks of 8 halves
            int base = idx8 * 8;
            int t = base % TP2, bc = base / TP2;
            H8 o;
            if (t < T_) {
                int b = bc >> 6;
                const float* dp = &data[bc * T_ + t];
                F4U d0, d1;
                d0.v = *(const float4*)dp; d1.v = *(const float4*)(dp + 4);
#pragma unroll
                for (int e = 0; e < 4; e++) {
                    o.e[e]     = (_Float16)(d0.f[e] * mval(mask, mode, b * T_ + t + e));
                    o.e[e + 4] = (_Float16)(d1.f[e] * mval(mask, mode, b * T_ + t + 4 + e));
                }
            } else {
#pragma unroll
                for (int e = 0; e < 8; e++) o.e[e] = (_Float16)0.f;
            }
            *(float4*)&dm[base] = o.v;
        }
        return;
    }
    __shared__ float mfS[8][72];
    __shared__ _Float16 sZ[64 * 40];
    __shared__ float2 rotS[2][16];
    __shared__ float cnS[8];
    int kk = tid >> 4, tq = tid & 15;          // 16 k-rows x 16 t-groups (4 t each)
    int k0 = blockIdx.x * 16;
    int k = k0 + kk;
    if (tid < 16) {
        int kq = k0 + tid;
        double om = 2.0 * M_PI * (fstep + (double)kq * fstep);
        double w = (double)((float)om);        // reference rounds omega to f32
        double s, c;
        sincos(w, &s, &c);        rotS[0][tid] = make_float2((float)c, (float)s);
        sincos(64.0 * w, &s, &c); rotS[1][tid] = make_float2((float)c, (float)s);
    }
    __syncthreads();
    float2 r1 = rotS[0][kk], r64 = rotS[1][kk];
    float2 r4 = cmul(r1, r1); r4 = cmul(r4, r4);
    float2 rtq = make_float2(1.f, 0.f);
    {
        float2 p = r4;
        if (tq & 1) rtq = cmul(rtq, p); p = cmul(p, p);
        if (tq & 2) rtq = cmul(rtq, p); p = cmul(p, p);
        if (tq & 4) rtq = cmul(rtq, p); p = cmul(p, p);
        if (tq & 8) rtq = cmul(rtq, p);
    }
    float2 rstart = cmul(r1, rtq);             // angle w*(4*tq + 1)
    float2 racc = make_float2(1.f, 0.f);       // w*64*tile
    bool valid = (k < K);
    float s2a[8], c2a[8], cn[8];
#pragma unroll
    for (int b = 0; b < 8; b++) { s2a[b] = 0.f; c2a[b] = 0.f; cn[b] = 0.f; }
    for (int a = 0; a < TP2 / 64; a++) {
        int t0 = a * 64;
        __syncthreads();   // previous tile's LDS consumers done
#pragma unroll
        for (int u = 0; u < 2; u++) {
            int idx = u * 256 + tid;
            int b = idx >> 6, cc = idx & 63;
            int t = t0 + cc;
            mfS[b][cc] = (t < T_) ? mval(mask, mode, b * T_ + t) : 0.f;
        }
        float2 rb = cmul(rstart, racc);
        float cf[4], sf[4];
#pragma unroll
        for (int e = 0; e < 4; e++) {
            int t = t0 + tq * 4 + e;
            bool ok = valid && (t < T_);
            cf[e] = ok ? rb.x : 0.f;
            sf[e] = ok ? rb.y : 0.f;
            rb = cmul(rb, r1);
        }
#pragma unroll
        for (int e = 0; e < 4; e++) {
            HP pk; pk.hh[0] = (_Float16)cf[e]; pk.hh[1] = (_Float16)sf[e];
            *(unsigned*)&sZ[(tq * 4 + e) * 40 + 2 * kk] = pk.u;
        }
        __syncthreads();   // mfS + sZ visible
        // tau sums (+ exact cnt on kk==0)
#pragma unroll
        for (int b = 0; b < 8; b++) {
            F4U mv; mv.v = *(const float4*)&mfS[b][tq * 4];
#pragma unroll
            for (int e = 0; e < 4; e++) {
                float m = mv.f[e];
                s2a[b] = fmaf(m, 2.f * sf[e] * cf[e], s2a[b]);
                c2a[b] = fmaf(m, (cf[e] - sf[e]) * (cf[e] + sf[e]), c2a[b]);
                if (kk == 0) cn[b] += m;
            }
        }
        // Z rows 2k (cos), 2k+1 (sin): 8B vector stores
        H4 hc, hs;
#pragma unroll
        for (int e = 0; e < 4; e++) { hc.e[e] = (_Float16)cf[e]; hs.e[e] = (_Float16)sf[e]; }
        size_t zoff = (size_t)(2 * k) * TP2 + t0 + tq * 4;
        *(float2*)&Zb[zoff] = hc.v;
        *(float2*)&Zb[zoff + TP2] = hs.v;
        // ZT[t][k2] from sZ: 2048 halves / 256 threads = 8 each
        {
            int row = tid >> 2, q = tid & 3;
            float4 z = *(const float4*)&sZ[row * 40 + q * 8];
            *(float4*)&ZT[(size_t)(t0 + row) * K2P + 2 * k0 + q * 8] = z;
        }
        racc = cmul(racc, r64);
    }
    // reduce tau + cnt over the 16 tq lanes
#pragma unroll
    for (int b = 0; b < 8; b++) {
        s2a[b] += __shfl_xor(s2a[b], 1); s2a[b] += __shfl_xor(s2a[b], 2);
        s2a[b] += __shfl_xor(s2a[b], 4); s2a[b] += __shfl_xor(s2a[b], 8);
        c2a[b] += __shfl_xor(c2a[b], 1); c2a[b] += __shfl_xor(c2a[b], 2);
        c2a[b] += __shfl_xor(c2a[b], 4); c2a[b] += __shfl_xor(c2a[b], 8);
        cn[b]  += __shfl_xor(cn[b], 1);  cn[b]  += __shfl_xor(cn[b], 2);
        cn[b]  += __shfl_xor(cn[b], 4);  cn[b]  += __shfl_xor(cn[b], 8);
    }
    if (tid == 0) {
#pragma unroll
        for (int b = 0; b < 8; b++) cnS[b] = cn[b];
    }
    __syncthreads();
    if (tq == 0) {
#pragma unroll
        for (int b = 0; b < 8; b++) {
            float s2 = s2a[b], c2 = c2a[b];
            float phi = 0.5f * atan2f(s2, c2);
            float cp = cosf(phi), sp = sinf(phi);
            float cnt = cnS[b];
            float A = 0.5f * (cnt + c2), D = 0.5f * (cnt - c2), E = 0.5f * s2;
            int kidx = b * KP + k;
            cphi[kidx] = cp; sphi[kidx] = sp;
            rdcv[kidx] = 1.f / (cp * cp * A + 2.f * cp * sp * E + sp * sp * D);
            rdsv[kidx] = 1.f / (sp * sp * A - 2.f * cp * sp * E + cp * cp * D);
        }
    }
}

// ---------------- shared 1-wave 64x64 GEMM core, counted-vmcnt dbuf pipeline ----------------
#define STAGE(BUFSEL, OFF) do {                                                \
        char* Ld_ = ldsb + (BUFSEL) * 16384;                                   \
        _Pragma("unroll")                                                      \
        for (int i_ = 0; i_ < 8; i_++)                                         \
            gload16(pA + (OFF) + sOff[i_], Ld_ + i_ * 1024 + lane * 16);       \
        _Pragma("unroll")                                                      \
        for (int i_ = 0; i_ < 8; i_++)                                         \
            gload16(pB + (OFF) + sOff[i_], Ld_ + 8192 + i_ * 1024 + lane * 16);\
    } while (0)

template <int NS>
__device__ __forceinline__ void gemm_core(
    const char* pA, const char* pB, int rstride, char* ldsb, int lane,
    f32x16& acc00, f32x16& acc01, f32x16& acc10, f32x16& acc11) {
    int sOff[8];
#pragma unroll
    for (int i = 0; i < 8; i++) {
        int g8 = i * 64 + lane;
        int r = g8 >> 3, c = g8 & 7;
        sOff[i] = r * rstride + ((c ^ (r & 7)) << 4);   // inverse-swizzled source
    }
    int ra = lane & 31, kg = lane >> 5, x = ra & 7;
    STAGE(0, 0);
    if (NS > 1) STAGE(1, 128);
    for (int s = 0; s < NS; s++) {
        if (s + 1 < NS) { asm volatile("s_waitcnt vmcnt(16)" ::: "memory"); }
        else            { asm volatile("s_waitcnt vmcnt(0)" ::: "memory"); }
        __builtin_amdgcn_sched_barrier(0);
        const char* LA = ldsb + (s & 1) * 16384;
        const char* LB = LA + 8192;
        h8 af0[4], af1[4], bf0[4], bf1[4];
#pragma unroll
        for (int ks = 0; ks < 4; ks++) {
            int c = ks * 2 + kg;
            af0[ks] = *(const h8*)(LA + ((ra * 8 + (c ^ x)) << 4));
            af1[ks] = *(const h8*)(LA + (((ra + 32) * 8 + (c ^ x)) << 4));
            bf0[ks] = *(const h8*)(LB + ((ra * 8 + (c ^ x)) << 4));
            bf1[ks] = *(const h8*)(LB + (((ra + 32) * 8 + (c ^ x)) << 4));
        }
        asm volatile("s_waitcnt lgkmcnt(0)" ::: "memory");   // reads done before DMA overwrite
        if (s + 2 < NS) STAGE(s & 1, (s + 2) * 128);
#pragma unroll
        for (int ks = 0; ks < 4; ks++) {
            acc00 = MFMA32(af0[ks], bf0[ks], acc00);
            acc01 = MFMA32(af0[ks], bf1[ks], acc01);
            acc10 = MFMA32(af1[ks], bf0[ks], acc10);
            acc11 = MFMA32(af1[ks], bf1[ks], acc11);
        }
    }
}

// ---------------- GEMM1: W[m][k2] = sum_t dm[m][t] * Z[k2][t], fused LS-combine ----------------
__global__ __launch_bounds__(64) void gemm1x(
    const _Float16* __restrict__ dm, const _Float16* __restrict__ Zb,
    const float* __restrict__ cphi, const float* __restrict__ sphi,
    const float* __restrict__ rdc, const float* __restrict__ rds,
    _Float16* __restrict__ Wout) {
    __shared__ _Float16 lds[16384];   // 32KB: 2 bufs x (A 8KB | B 8KB)
    int bid = blockIdx.x;                  // 1216 = 8 XCD * 152
    int c8 = bid & 7, j = bid >> 3;
    int nt = c8 * 19 + (j >> 3);           // B-panel shared by 8 consecutive blocks/XCD
    int mt = j & 7;
    int m0 = mt * 64, n0 = nt * 64;
    int lane = threadIdx.x;
    f32x16 acc00 = Z16v, acc01 = Z16v, acc10 = Z16v, acc11 = Z16v;
    gemm_core<NS1>((const char*)dm + (size_t)m0 * 2560,
                   (const char*)Zb + (size_t)n0 * 2560,
                   2560, (char*)lds, lane, acc00, acc01, acc10, acc11);
    int bb = mt;                            // tile M=64 aligns with batch dim
    int colk = lane & 31, rb4 = (lane >> 5) * 4;
#define EPI1(ACC, I, J) {                                                      \
        int k2 = n0 + 32 * (J) + colk;                                         \
        int kidx = bb * KP + (k2 >> 1);                                        \
        float cp = cphi[kidx], sp = sphi[kidx];                                \
        float rc_ = rdc[kidx], rs_ = rds[kidx];                                \
        int par = k2 & 1;                                                      \
        _Pragma("unroll")                                                      \
        for (int reg = 0; reg < 16; reg++) {                                   \
            float own = (ACC)[reg];                                            \
            float oth = __shfl_xor(own, 1);                                    \
            float p = par ? oth : own, q = par ? own : oth;                    \
            float cc = (cp * p + sp * q) * rc_;                                \
            float sc = (cp * q - sp * p) * rs_;                                \
            float val = par ? (sp * cc + cp * sc) : (cp * cc - sp * sc);       \
            int row = m0 + 32 * (I) + rb4 + (reg & 3) + 8 * (reg >> 2);        \
            Wout[(size_t)row * K2P + k2] = (_Float16)val;                      \
        } }
    EPI1(acc00, 0, 0); EPI1(acc01, 0, 1); EPI1(acc10, 1, 0); EPI1(acc11, 1, 1);
#undef EPI1
}

// ---------------- GEMM2: rpart[sk][m][t] = sum_{k2 chunk} W[m][k2] * ZT[t][k2] ----------------
__global__ __launch_bounds__(64) void gemm2x(
    const _Float16* __restrict__ Wm, const _Float16* __restrict__ ZT,
    float* __restrict__ rpart) {
    __shared__ _Float16 lds[16384];
    int bid = blockIdx.x;                  // 1280 = 8 XCD * 160
    int c8 = bid & 7, j = bid >> 3;
    int g2 = c8 * 20 + (j >> 3);           // 0..159 -> (nt, sk)
    int nt = g2 >> 3, sk = g2 & 7;
    int mt = j & 7;
    int m0 = mt * 64, t0 = nt * 64;
    int lane = threadIdx.x;
    f32x16 acc00 = Z16v, acc01 = Z16v, acc10 = Z16v, acc11 = Z16v;
    gemm_core<NS2>((const char*)Wm + (size_t)m0 * 19456 + sk * 2432,
                   (const char*)ZT + (size_t)t0 * 19456 + sk * 2432,
                   19456, (char*)lds, lane, acc00, acc01, acc10, acc11);
    int colk = lane & 31, rb4 = (lane >> 5) * 4;
#define EPI2(ACC, I, J) {                                                      \
        int t = t0 + 32 * (J) + colk;                                          \
        _Pragma("unroll")                                                      \
        for (int reg = 0; reg < 16; reg++) {                                   \
            int row = m0 + 32 * (I) + rb4 + (reg & 3) + 8 * (reg >> 2);        \
            rpart[(size_t)(sk * M_ + row) * TP2 + t] = (ACC)[reg];             \
        } }
    EPI2(acc00, 0, 0); EPI2(acc01, 0, 1); EPI2(acc10, 1, 0); EPI2(acc11, 1, 1);
#undef EPI2
}

// ---------------- normalize + select (mask converted in-block, exact cnt) ----------------
__global__ __launch_bounds__(256) void norm3_kernel(
    const float* __restrict__ rpart, const float* __restrict__ data,
    const void* __restrict__ mask, float* __restrict__ out) {
    int mode = detect_mode(mask);
    __shared__ float rsum[T_];
    __shared__ float msh[T_];
    __shared__ float4 red4[256];
    __shared__ float redc[256];
    __shared__ float s_scale;
    int bc = blockIdx.x, b = bc >> 6;
    const size_t rbase = (size_t)bc * TP2;
    const size_t dbase = (size_t)bc * T_;
    const size_t rstr = (size_t)M_ * TP2;
    float sr = 0.f, srr = 0.f, sd = 0.f, sdd = 0.f, cnp = 0.f;
    for (int t = threadIdx.x; t < T_; t += 256) {
        float r = 0.f;
#pragma unroll
        for (int s = 0; s < SPLITK; s++) r += rpart[s * rstr + rbase + t];
        rsum[t] = r;
        float m = mval(mask, mode, b * T_ + t);
        msh[t] = m;
        float xv = data[dbase + t];
        sr += r; srr += r * r; sd += xv * m; sdd += xv * xv * m; cnp += m;
    }
    red4[threadIdx.x] = make_float4(sr, srr, sd, sdd);
    redc[threadIdx.x] = cnp;
    __syncthreads();
    for (int w = 128; w > 0; w >>= 1) {
        if (threadIdx.x < w) {
            float4 a = red4[threadIdx.x], c = red4[threadIdx.x + w];
            red4[threadIdx.x] = make_float4(a.x + c.x, a.y + c.y, a.z + c.z, a.w + c.w);
            redc[threadIdx.x] += redc[threadIdx.x + w];
        }
        __syncthreads();
    }
    if (threadIdx.x == 0) {
        float4 v = red4[0];
        float cnt = redc[0];
        float varr = (v.y - v.x * v.x / (float)T_) / (float)(T_ - 1);
        float vard = (v.w - v.z * v.z / cnt) / (cnt - 1.f);
        s_scale = sqrtf(vard / varr);
    }
    __syncthreads();
    float scale = s_scale;
    for (int t = threadIdx.x; t < T_; t += 256) {
        out[dbase + t] = (msh[t] > 0.5f) ? data[dbase + t] : rsum[t] * scale;
    }
}

extern "C" void kernel_launch(void* const* d_in, const int* in_sizes, int n_in,
                              void* d_out, int out_size, void* d_ws, size_t ws_size,
                              hipStream_t stream) {
    const float* data = (const float*)d_in[0];
    const void* mask = d_in[1];
    float* out = (float*)d_out;

    // Replicate numpy arange length computation exactly (double precision).
    const double timespan = 1.0 * (T_ + 1) - 1.0;               // 1200
    const double fstep = 1.0 / (timespan * 8.0);                // OSFREQ = 8
    const double stop = (1.0 * (double)T_) / (2.0 * timespan) + fstep;
    const int K = (int)ceil((stop - fstep) / fstep);            // 4800 (or 4801)

    char* w = (char*)d_ws;
    auto alloc = [&](size_t nbytes) {
        char* p = w;
        w += ((nbytes + 255) / 256) * 256;
        return p;
    };
    float*     cphi  = (float*)    alloc((size_t)B_ * KP * 4);
    float*     sphi  = (float*)    alloc((size_t)B_ * KP * 4);
    float*     rdc   = (float*)    alloc((size_t)B_ * KP * 4);
    float*     rds   = (float*)    alloc((size_t)B_ * KP * 4);
    _Float16*  dm_h  = (_Float16*) alloc((size_t)M_ * TP2 * 2);
    _Float16*  Z     = (_Float16*) alloc((size_t)K2P * TP2 * 2);
    _Float16*  ZT    = (_Float16*) alloc((size_t)TP2 * K2P * 2);
    _Float16*  W     = (_Float16*) alloc((size_t)M_ * K2P * 2);
    float*     rpart = (float*)    alloc((size_t)SPLITK * M_ * TP2 * 4);
    (void)ws_size; (void)in_sizes; (void)n_in; (void)out_size;

    basisC_kernel<<<314, 256, 0, stream>>>(mask, data, Z, ZT, dm_h,
                                           cphi, sphi, rdc, rds, K, fstep);
    gemm1x<<<1216, 64, 0, stream>>>(dm_h, Z, cphi, sphi, rdc, rds, W);
    gemm2x<<<1280, 64, 0, stream>>>(W, ZT, rpart);
    norm3_kernel<<<M_, 256, 0, stream>>>(rpart, data, mask, out);
}